// Round 3
// baseline (731.143 us; speedup 1.0000x reference)
//
#include <hip/hip_runtime.h>

#define N_NODES 100000
#define N_EDGES 1600000
#define NEG_SLOPE 0.2f

typedef __bf16 bf16x8 __attribute__((ext_vector_type(8)));
typedef float f32x4 __attribute__((ext_vector_type(4)));

__device__ inline unsigned short f2bf(float f) {
    union { float f; unsigned u; } x; x.f = f;
    unsigned r = x.u + 0x7fffu + ((x.u >> 16) & 1u);   // round-to-nearest-even
    return (unsigned short)(r >> 16);
}

// ---- W_src / W_dst -> bf16, pre-swizzled into MFMA B-fragment order --------
// For element (k, n): lane = ((k&31)>>3)*16 + (n&15), j = k&7  (validated R1)
// Wsw_src elems: [ct(16)][ks(8)][lane(64)][j(8)]          (ks = k>>5)
// Wsw_dst elems: [stage(2)][ct(16)][ks4(4)][lane(64)][j(8)] (stage=k>>7, ks4=(k>>5)&3)
__global__ __launch_bounds__(256) void cvt_w_k(const float* __restrict__ Ws,
                                               const float* __restrict__ Wd,
                                               unsigned short* __restrict__ Wsw_src,
                                               unsigned short* __restrict__ Wsw_dst) {
    int idx = blockIdx.x * 256 + threadIdx.x;        // 0..131071
    int sel = idx >> 16;
    int r = idx & 65535;
    int k = r >> 8, n = r & 255;
    int ct = n >> 4, nl = n & 15;
    int kk = k & 31;
    int lane = (kk >> 3) * 16 + nl, j = k & 7;
    if (sel == 0) {
        int ks = k >> 5;
        Wsw_src[(ct * 8 + ks) * 512 + lane * 8 + j] = f2bf(Ws[k * 256 + n]);
    } else {
        int stage = k >> 7, ks4 = (k >> 5) & 3;
        Wsw_dst[((stage * 16 + ct) * 4 + ks4) * 512 + lane * 8 + j] = f2bf(Wd[k * 256 + n]);
    }
}

// ---- h_dst GEMM: out[100000,256] = feat @ W_dst + b_dst (bf16 MFMA) --------
// Block: 256 thr (4 waves), tile 64 rows x 256 cols; K=256 in two LDS stages.
__global__ __launch_bounds__(256) void hdst_k(const float* __restrict__ feat,
                                              const unsigned short* __restrict__ Wsw_dst,
                                              const float* __restrict__ b_dst,
                                              float* __restrict__ out) {
    __shared__ unsigned short Blds[32768];           // 64 KB: [ct16][ks4][512]
    int tid = threadIdx.x, mb = blockIdx.x;
    int wave = tid >> 6, lane = tid & 63;
    int quad = lane >> 4, l16 = lane & 15;
    int row_strip = mb * 64 + wave * 16;
    int arow = row_strip + l16;
    if (arow >= N_NODES) arow = N_NODES - 1;         // clamp loads; stores guarded
    const float* arow_p = feat + (size_t)arow * 256;

    f32x4 acc[16];
    #pragma unroll
    for (int c = 0; c < 16; ++c) acc[c] = (f32x4){0.f, 0.f, 0.f, 0.f};

    for (int stage = 0; stage < 2; ++stage) {
        if (stage) __syncthreads();
        {   // stage 64 KB of pre-swizzled B: 4096 x 16B, coalesced
            const uint4* s4 = (const uint4*)(Wsw_dst + stage * 32768);
            uint4* d4 = (uint4*)Blds;
            #pragma unroll 4
            for (int i = tid; i < 4096; i += 256) d4[i] = s4[i];
        }
        __syncthreads();
        #pragma unroll
        for (int ks4 = 0; ks4 < 4; ++ks4) {
            int k0 = stage * 128 + ks4 * 32 + quad * 8;
            float4 f0 = *(const float4*)(arow_p + k0);
            float4 f1 = *(const float4*)(arow_p + k0 + 4);
            union { unsigned short u[8]; bf16x8 v; } cv;
            cv.u[0] = f2bf(f0.x); cv.u[1] = f2bf(f0.y);
            cv.u[2] = f2bf(f0.z); cv.u[3] = f2bf(f0.w);
            cv.u[4] = f2bf(f1.x); cv.u[5] = f2bf(f1.y);
            cv.u[6] = f2bf(f1.z); cv.u[7] = f2bf(f1.w);
            bf16x8 a = cv.v;                         // A[m=lane&15][k=quad*8+j]
            #pragma unroll
            for (int ct = 0; ct < 16; ++ct) {
                bf16x8 b = *(const bf16x8*)(&Blds[(ct * 4 + ks4) * 512 + lane * 8]);
                acc[ct] = __builtin_amdgcn_mfma_f32_16x16x32_bf16(a, b, acc[ct], 0, 0, 0);
            }
        }
    }
    // C/D: col = lane&15, row = quad*4 + reg
    #pragma unroll
    for (int ct = 0; ct < 16; ++ct) {
        int col = ct * 16 + l16;
        #pragma unroll
        for (int r = 0; r < 4; ++r) {
            int row = row_strip + quad * 4 + r;
            if (row < N_NODES)
                out[(size_t)row * 256 + col] = acc[ct][r] + b_dst[col];
        }
    }
}

// ---- attention logit projections (f32): a_src[N,4], a_dst[N,4] -------------
__global__ __launch_bounds__(256) void aproj_k(const float* __restrict__ feat,
                                               const float* __restrict__ Was,
                                               const float* __restrict__ Wad,
                                               float* __restrict__ a_src,
                                               float* __restrict__ a_dst) {
    int node = blockIdx.x * 4 + (threadIdx.x >> 6);
    int lane = threadIdx.x & 63;
    const float* row = feat + (size_t)node * 256;
    float as[4] = {0, 0, 0, 0}, ad[4] = {0, 0, 0, 0};
    #pragma unroll
    for (int c = 0; c < 4; ++c) {
        int k = c * 64 + lane;
        float f = row[k];
        float4 ws = *(const float4*)(Was + k * 4);
        float4 wd = *(const float4*)(Wad + k * 4);
        as[0] += f * ws.x; as[1] += f * ws.y; as[2] += f * ws.z; as[3] += f * ws.w;
        ad[0] += f * wd.x; ad[1] += f * wd.y; ad[2] += f * wd.z; ad[3] += f * wd.w;
    }
    #pragma unroll
    for (int off = 32; off > 0; off >>= 1) {
        #pragma unroll
        for (int h = 0; h < 4; ++h) {
            as[h] += __shfl_xor(as[h], off);
            ad[h] += __shfl_xor(ad[h], off);
        }
    }
    if (lane == 0) {
        #pragma unroll
        for (int h = 0; h < 4; ++h) {
            a_src[node * 4 + h] = as[h];
            a_dst[node * 4 + h] = ad[h];
        }
    }
}

// ---- CSR row pointers from sorted dst --------------------------------------
__global__ void rowptr_k(const int* __restrict__ dst, int* __restrict__ rp) {
    int n = blockIdx.x * 256 + threadIdx.x;
    if (n > N_NODES) return;
    int lo = 0, hi = N_EDGES;                        // first i with dst[i] >= n
    while (lo < hi) { int mid = (lo + hi) >> 1; if (dst[mid] < n) lo = mid + 1; else hi = mid; }
    rp[n] = lo;
}

// ---- fused: edge softmax + feature aggregation + MFMA projection -----------
// Block: 256 thr (4 waves), 16 dst nodes. Wave w gathers nodes w*4..w*4+3:
//   g_h[256] = sum_e a_eh * feat[src_e]  (f32 regs, 4 cols/lane), -> bf16 LDS.
// Then wave w = head w projects: out[16 nodes, head cols] += g @ W_src_head.
// G LDS layout [h(4)][g8(32)][m(17 pad)][j(8)] bf16: MFMA ds_read_b128
// conflict-free (consecutive m = consecutive 16B).
__global__ __launch_bounds__(256) void agg_k(const int* __restrict__ src,
                                             const int* __restrict__ rp,
                                             const float* __restrict__ a_src,
                                             const float* __restrict__ a_dst,
                                             const float* __restrict__ feat,
                                             const unsigned short* __restrict__ Wsw_src,
                                             float* __restrict__ out) {
    __shared__ unsigned short G[4 * 32 * 17 * 8];    // 34,816 B
    __shared__ float wbuf[4][64][4];                 //  4,096 B
    int tid = threadIdx.x, wave = tid >> 6, lane = tid & 63;
    int base = blockIdx.x * 16;

    // ---------------- gather phase ----------------
    for (int i = 0; i < 4; ++i) {
        int m = wave * 4 + i;
        int node = base + m;
        int r0 = rp[node], r1 = rp[node + 1];
        f32x4 g0 = {0.f,0.f,0.f,0.f}, g1 = g0, g2 = g0, g3 = g0;
        if (r0 < r1) {
            float4 adv = *(const float4*)(a_dst + node * 4);
            // pass 1: per-head max of leaky_relu(a_src[s]+a_dst[n])
            float m0 = -1e30f, m1 = -1e30f, m2 = -1e30f, m3 = -1e30f;
            for (int e = r0 + lane; e < r1; e += 64) {
                int s = src[e];
                float4 av = *(const float4*)(a_src + s * 4);
                float e0 = av.x + adv.x; e0 = e0 > 0.f ? e0 : NEG_SLOPE * e0;
                float e1 = av.y + adv.y; e1 = e1 > 0.f ? e1 : NEG_SLOPE * e1;
                float e2 = av.z + adv.z; e2 = e2 > 0.f ? e2 : NEG_SLOPE * e2;
                float e3 = av.w + adv.w; e3 = e3 > 0.f ? e3 : NEG_SLOPE * e3;
                m0 = fmaxf(m0, e0); m1 = fmaxf(m1, e1);
                m2 = fmaxf(m2, e2); m3 = fmaxf(m3, e3);
            }
            #pragma unroll
            for (int off = 32; off > 0; off >>= 1) {
                m0 = fmaxf(m0, __shfl_xor(m0, off));
                m1 = fmaxf(m1, __shfl_xor(m1, off));
                m2 = fmaxf(m2, __shfl_xor(m2, off));
                m3 = fmaxf(m3, __shfl_xor(m3, off));
            }
            // pass 2: denominators
            float d0 = 0.f, d1 = 0.f, d2 = 0.f, d3 = 0.f;
            for (int e = r0 + lane; e < r1; e += 64) {
                int s = src[e];
                float4 av = *(const float4*)(a_src + s * 4);
                float e0 = av.x + adv.x; e0 = e0 > 0.f ? e0 : NEG_SLOPE * e0;
                float e1 = av.y + adv.y; e1 = e1 > 0.f ? e1 : NEG_SLOPE * e1;
                float e2 = av.z + adv.z; e2 = e2 > 0.f ? e2 : NEG_SLOPE * e2;
                float e3 = av.w + adv.w; e3 = e3 > 0.f ? e3 : NEG_SLOPE * e3;
                d0 += __expf(e0 - m0); d1 += __expf(e1 - m1);
                d2 += __expf(e2 - m2); d3 += __expf(e3 - m3);
            }
            #pragma unroll
            for (int off = 32; off > 0; off >>= 1) {
                d0 += __shfl_xor(d0, off); d1 += __shfl_xor(d1, off);
                d2 += __shfl_xor(d2, off); d3 += __shfl_xor(d3, off);
            }
            float i0 = 1.f / d0, i1 = 1.f / d1, i2 = 1.f / d2, i3 = 1.f / d3;
            // pass 3: chunks of 64 edges; per-edge weights once into LDS
            for (int c0 = r0; c0 < r1; c0 += 64) {
                int cnt = min(64, r1 - c0);
                if (lane < cnt) {
                    int s = src[c0 + lane];
                    float4 av = *(const float4*)(a_src + s * 4);
                    float e0 = av.x + adv.x; e0 = e0 > 0.f ? e0 : NEG_SLOPE * e0;
                    float e1 = av.y + adv.y; e1 = e1 > 0.f ? e1 : NEG_SLOPE * e1;
                    float e2 = av.z + adv.z; e2 = e2 > 0.f ? e2 : NEG_SLOPE * e2;
                    float e3 = av.w + adv.w; e3 = e3 > 0.f ? e3 : NEG_SLOPE * e3;
                    float4 w; w.x = __expf(e0 - m0) * i0; w.y = __expf(e1 - m1) * i1;
                    w.z = __expf(e2 - m2) * i2; w.w = __expf(e3 - m3) * i3;
                    *(float4*)&wbuf[wave][lane][0] = w;
                }
                for (int j = 0; j < cnt; ++j) {
                    int s = src[c0 + j];
                    float4 w4 = *(const float4*)&wbuf[wave][j][0];   // broadcast
                    f32x4 f = *(const f32x4*)(feat + (size_t)s * 256 + lane * 4);
                    g0 += w4.x * f; g1 += w4.y * f;
                    g2 += w4.z * f; g3 += w4.w * f;
                }
            }
        }
        // write g (zeros if no edges): lane owns cols lane*4..+3
        int g8 = lane >> 1, off4 = (lane & 1) * 4;
        ushort4 u;
        u.x = f2bf(g0[0]); u.y = f2bf(g0[1]); u.z = f2bf(g0[2]); u.w = f2bf(g0[3]);
        *(ushort4*)&G[((0 * 32 + g8) * 17 + m) * 8 + off4] = u;
        u.x = f2bf(g1[0]); u.y = f2bf(g1[1]); u.z = f2bf(g1[2]); u.w = f2bf(g1[3]);
        *(ushort4*)&G[((1 * 32 + g8) * 17 + m) * 8 + off4] = u;
        u.x = f2bf(g2[0]); u.y = f2bf(g2[1]); u.z = f2bf(g2[2]); u.w = f2bf(g2[3]);
        *(ushort4*)&G[((2 * 32 + g8) * 17 + m) * 8 + off4] = u;
        u.x = f2bf(g3[0]); u.y = f2bf(g3[1]); u.z = f2bf(g3[2]); u.w = f2bf(g3[3]);
        *(ushort4*)&G[((3 * 32 + g8) * 17 + m) * 8 + off4] = u;
    }
    __syncthreads();

    // ---------------- projection phase: wave = head ----------------
    int h = wave, quad = lane >> 4, l16 = lane & 15;
    bf16x8 afr[8];
    #pragma unroll
    for (int ks = 0; ks < 8; ++ks)                   // A[m=l16][k=quad*8+j]
        afr[ks] = *(const bf16x8*)&G[((h * 32 + ks * 4 + quad) * 17 + l16) * 8];
    const bf16x8* W8 = (const bf16x8*)Wsw_src;
    #pragma unroll
    for (int ct = 0; ct < 4; ++ct) {
        f32x4 acc = {0.f, 0.f, 0.f, 0.f};
        #pragma unroll
        for (int ks = 0; ks < 8; ++ks) {
            bf16x8 b = W8[((h * 4 + ct) * 8 + ks) * 64 + lane];
            acc = __builtin_amdgcn_mfma_f32_16x16x32_bf16(afr[ks], b, acc, 0, 0, 0);
        }
        #pragma unroll
        for (int r = 0; r < 4; ++r) {                // row = quad*4+r, col = l16
            int node = base + quad * 4 + r;
            float* p = out + (size_t)node * 256 + h * 64 + ct * 16 + l16;
            *p += acc[r];
        }
    }
}

extern "C" void kernel_launch(void* const* d_in, const int* in_sizes, int n_in,
                              void* d_out, int out_size, void* d_ws, size_t ws_size,
                              hipStream_t stream) {
    const float* feat   = (const float*)d_in[0];
    const float* W_src  = (const float*)d_in[1];
    const float* W_dst  = (const float*)d_in[2];
    const float* b_dst  = (const float*)d_in[3];
    const float* Wa_src = (const float*)d_in[4];
    const float* Wa_dst = (const float*)d_in[5];
    const int*   src    = (const int*)d_in[6];
    const int*   dst    = (const int*)d_in[7];
    float* out = (float*)d_out;

    // ws footprint: 3,862,148 B total (R1/R2 failures suspected ws overflow)
    char* ws = (char*)d_ws;
    unsigned short* Wsw_src = (unsigned short*)(ws);               // 131,072 B
    unsigned short* Wsw_dst = (unsigned short*)(ws + 131072);      // 131,072 B
    float* a_src            = (float*)(ws + 262144);               // 1,600,000 B
    float* a_dst            = (float*)(ws + 1862144);              // 1,600,000 B
    int*   rp               = (int*)(ws + 3462144);                // 400,004 B

    hipLaunchKernelGGL(cvt_w_k,  dim3(512),   dim3(256), 0, stream, W_src, W_dst, Wsw_src, Wsw_dst);
    hipLaunchKernelGGL(aproj_k,  dim3(25000), dim3(256), 0, stream, feat, Wa_src, Wa_dst, a_src, a_dst);
    hipLaunchKernelGGL(rowptr_k, dim3(391),   dim3(256), 0, stream, dst, rp);
    hipLaunchKernelGGL(hdst_k,   dim3(1563),  dim3(256), 0, stream, feat, Wsw_dst, b_dst, out);
    hipLaunchKernelGGL(agg_k,    dim3(6250),  dim3(256), 0, stream, src, rp, a_src, a_dst, feat, Wsw_src, out);
}

// Round 4
// 564.332 us; speedup vs baseline: 1.2956x; 1.2956x over previous
//
#include <hip/hip_runtime.h>

#define N_NODES 100000
#define N_EDGES 1600000
#define NEG_SLOPE 0.2f

typedef __bf16 bf16x8 __attribute__((ext_vector_type(8)));
typedef float f32x4 __attribute__((ext_vector_type(4)));

__device__ inline unsigned short f2bf(float f) {
    union { float f; unsigned u; } x; x.f = f;
    unsigned r = x.u + 0x7fffu + ((x.u >> 16) & 1u);   // round-to-nearest-even
    return (unsigned short)(r >> 16);
}

// ---- W_src / W_dst -> bf16, pre-swizzled into MFMA B-fragment order --------
// For element (k, n): lane = ((k&31)>>3)*16 + (n&15), j = k&7  (validated R1/R3)
// Both layouts: [ct(16)][ks(8)][lane(64)][j(8)]   (ct = n>>4, ks = k>>5)
__global__ __launch_bounds__(256) void cvt_w_k(const float* __restrict__ Ws,
                                               const float* __restrict__ Wd,
                                               unsigned short* __restrict__ Wsw_src,
                                               unsigned short* __restrict__ Wsw_dst) {
    int idx = blockIdx.x * 256 + threadIdx.x;        // 0..131071
    int sel = idx >> 16;
    int r = idx & 65535;
    int k = r >> 8, n = r & 255;
    int ct = n >> 4, nl = n & 15;
    int lane = ((k & 31) >> 3) * 16 + nl, j = k & 7;
    int ks = k >> 5;
    unsigned short v = f2bf((sel == 0 ? Ws : Wd)[k * 256 + n]);
    (sel == 0 ? Wsw_src : Wsw_dst)[(ct * 8 + ks) * 512 + lane * 8 + j] = v;
}

// ---- attention logit projections (f32): a_src[N,4], a_dst[N,4] -------------
__global__ __launch_bounds__(256) void aproj_k(const float* __restrict__ feat,
                                               const float* __restrict__ Was,
                                               const float* __restrict__ Wad,
                                               float* __restrict__ a_src,
                                               float* __restrict__ a_dst) {
    int node = blockIdx.x * 4 + (threadIdx.x >> 6);
    int lane = threadIdx.x & 63;
    const float* row = feat + (size_t)node * 256;
    float as[4] = {0, 0, 0, 0}, ad[4] = {0, 0, 0, 0};
    #pragma unroll
    for (int c = 0; c < 4; ++c) {
        int k = c * 64 + lane;
        float f = row[k];
        float4 ws = *(const float4*)(Was + k * 4);
        float4 wd = *(const float4*)(Wad + k * 4);
        as[0] += f * ws.x; as[1] += f * ws.y; as[2] += f * ws.z; as[3] += f * ws.w;
        ad[0] += f * wd.x; ad[1] += f * wd.y; ad[2] += f * wd.z; ad[3] += f * wd.w;
    }
    #pragma unroll
    for (int off = 32; off > 0; off >>= 1) {
        #pragma unroll
        for (int h = 0; h < 4; ++h) {
            as[h] += __shfl_xor(as[h], off);
            ad[h] += __shfl_xor(ad[h], off);
        }
    }
    if (lane == 0) {
        #pragma unroll
        for (int h = 0; h < 4; ++h) {
            a_src[node * 4 + h] = as[h];
            a_dst[node * 4 + h] = ad[h];
        }
    }
}

// ---- CSR row pointers from sorted dst --------------------------------------
__global__ void rowptr_k(const int* __restrict__ dst, int* __restrict__ rp) {
    int n = blockIdx.x * 256 + threadIdx.x;
    if (n > N_NODES) return;
    int lo = 0, hi = N_EDGES;                        // first i with dst[i] >= n
    while (lo < hi) { int mid = (lo + hi) >> 1; if (dst[mid] < n) lo = mid + 1; else hi = mid; }
    rp[n] = lo;
}

// ---- fused: edge softmax + feature aggregation + MFMA proj + h_dst ---------
// Block: 256 thr (4 waves), 16 dst nodes. Wave w gathers nodes w*4..w*4+3:
//   g_h[256] = sum_e a_eh * feat[src_e]  (f32 regs, 4 cols/lane) -> bf16 LDS.
// Per-edge (s, w) broadcast via __shfl(., j) (readlane) — no dependent
// src->feat pointer chain (R3: that chain made agg latency-bound at 465us).
// Projection: wave h computes out cols h*64..h*64+63 for all 16 nodes:
//   acc = g @ W_src[head h]  +  feat[dst rows] @ W_dst[col slice]  (+ b_dst)
// and stores out once (no RMW; hdst_k eliminated).
__global__ __launch_bounds__(256) void agg_k(const int* __restrict__ src,
                                             const int* __restrict__ rp,
                                             const float* __restrict__ a_src,
                                             const float* __restrict__ a_dst,
                                             const float* __restrict__ feat,
                                             const unsigned short* __restrict__ Wsw_src,
                                             const unsigned short* __restrict__ Wsw_dst,
                                             const float* __restrict__ b_dst,
                                             float* __restrict__ out) {
    __shared__ unsigned short G[4 * 32 * 17 * 8];    // 34,816 B
    int tid = threadIdx.x, wave = tid >> 6, lane = tid & 63;
    int base = blockIdx.x * 16;

    // ---------------- gather phase ----------------
    for (int i = 0; i < 4; ++i) {
        int m = wave * 4 + i;
        int node = base + m;
        int r0 = rp[node], r1 = rp[node + 1];
        f32x4 g0 = {0.f,0.f,0.f,0.f}, g1 = g0, g2 = g0, g3 = g0;
        if (r0 < r1) {
            float4 adv = *(const float4*)(a_dst + node * 4);
            // pass 1: per-head max of leaky_relu(a_src[s]+a_dst[n])
            float m0 = -1e30f, m1 = -1e30f, m2 = -1e30f, m3 = -1e30f;
            for (int e = r0 + lane; e < r1; e += 64) {
                int s = src[e];
                float4 av = *(const float4*)(a_src + s * 4);
                float e0 = av.x + adv.x; e0 = e0 > 0.f ? e0 : NEG_SLOPE * e0;
                float e1 = av.y + adv.y; e1 = e1 > 0.f ? e1 : NEG_SLOPE * e1;
                float e2 = av.z + adv.z; e2 = e2 > 0.f ? e2 : NEG_SLOPE * e2;
                float e3 = av.w + adv.w; e3 = e3 > 0.f ? e3 : NEG_SLOPE * e3;
                m0 = fmaxf(m0, e0); m1 = fmaxf(m1, e1);
                m2 = fmaxf(m2, e2); m3 = fmaxf(m3, e3);
            }
            #pragma unroll
            for (int off = 32; off > 0; off >>= 1) {
                m0 = fmaxf(m0, __shfl_xor(m0, off));
                m1 = fmaxf(m1, __shfl_xor(m1, off));
                m2 = fmaxf(m2, __shfl_xor(m2, off));
                m3 = fmaxf(m3, __shfl_xor(m3, off));
            }
            // pass 2: denominators
            float d0 = 0.f, d1 = 0.f, d2 = 0.f, d3 = 0.f;
            for (int e = r0 + lane; e < r1; e += 64) {
                int s = src[e];
                float4 av = *(const float4*)(a_src + s * 4);
                float e0 = av.x + adv.x; e0 = e0 > 0.f ? e0 : NEG_SLOPE * e0;
                float e1 = av.y + adv.y; e1 = e1 > 0.f ? e1 : NEG_SLOPE * e1;
                float e2 = av.z + adv.z; e2 = e2 > 0.f ? e2 : NEG_SLOPE * e2;
                float e3 = av.w + adv.w; e3 = e3 > 0.f ? e3 : NEG_SLOPE * e3;
                d0 += __expf(e0 - m0); d1 += __expf(e1 - m1);
                d2 += __expf(e2 - m2); d3 += __expf(e3 - m3);
            }
            #pragma unroll
            for (int off = 32; off > 0; off >>= 1) {
                d0 += __shfl_xor(d0, off); d1 += __shfl_xor(d1, off);
                d2 += __shfl_xor(d2, off); d3 += __shfl_xor(d3, off);
            }
            float i0 = 1.f / d0, i1 = 1.f / d1, i2 = 1.f / d2, i3 = 1.f / d3;
            // pass 3: chunks of 64 edges; lane l owns edge c0+l's (s, w);
            // inner loop broadcasts via readlane — loads stay independent.
            for (int c0 = r0; c0 < r1; c0 += 64) {
                int cnt = min(64, r1 - c0);
                int s = 0; float4 w = {0.f, 0.f, 0.f, 0.f};
                if (lane < cnt) {
                    s = src[c0 + lane];
                    float4 av = *(const float4*)(a_src + s * 4);
                    float e0 = av.x + adv.x; e0 = e0 > 0.f ? e0 : NEG_SLOPE * e0;
                    float e1 = av.y + adv.y; e1 = e1 > 0.f ? e1 : NEG_SLOPE * e1;
                    float e2 = av.z + adv.z; e2 = e2 > 0.f ? e2 : NEG_SLOPE * e2;
                    float e3 = av.w + adv.w; e3 = e3 > 0.f ? e3 : NEG_SLOPE * e3;
                    w.x = __expf(e0 - m0) * i0; w.y = __expf(e1 - m1) * i1;
                    w.z = __expf(e2 - m2) * i2; w.w = __expf(e3 - m3) * i3;
                }
                for (int j = 0; j < cnt; ++j) {
                    int sj   = __shfl(s, j);
                    float wx = __shfl(w.x, j), wy = __shfl(w.y, j);
                    float wz = __shfl(w.z, j), ww = __shfl(w.w, j);
                    f32x4 f = *(const f32x4*)(feat + (size_t)sj * 256 + lane * 4);
                    g0 += wx * f; g1 += wy * f;
                    g2 += wz * f; g3 += ww * f;
                }
            }
        }
        // write g (zeros if no edges): lane owns cols lane*4..+3
        int g8 = lane >> 1, off4 = (lane & 1) * 4;
        ushort4 u;
        u.x = f2bf(g0[0]); u.y = f2bf(g0[1]); u.z = f2bf(g0[2]); u.w = f2bf(g0[3]);
        *(ushort4*)&G[((0 * 32 + g8) * 17 + m) * 8 + off4] = u;
        u.x = f2bf(g1[0]); u.y = f2bf(g1[1]); u.z = f2bf(g1[2]); u.w = f2bf(g1[3]);
        *(ushort4*)&G[((1 * 32 + g8) * 17 + m) * 8 + off4] = u;
        u.x = f2bf(g2[0]); u.y = f2bf(g2[1]); u.z = f2bf(g2[2]); u.w = f2bf(g2[3]);
        *(ushort4*)&G[((2 * 32 + g8) * 17 + m) * 8 + off4] = u;
        u.x = f2bf(g3[0]); u.y = f2bf(g3[1]); u.z = f2bf(g3[2]); u.w = f2bf(g3[3]);
        *(ushort4*)&G[((3 * 32 + g8) * 17 + m) * 8 + off4] = u;
    }
    __syncthreads();

    // ---------------- projection phase: wave = head = out-col slice ----------
    int h = wave, quad = lane >> 4, l16 = lane & 15;
    f32x4 acc[4];
    #pragma unroll
    for (int c = 0; c < 4; ++c) acc[c] = (f32x4){0.f, 0.f, 0.f, 0.f};

    // part 1: g @ W_src[head h]  (A from G in LDS)
    const bf16x8* Ws8 = (const bf16x8*)Wsw_src;
    #pragma unroll
    for (int ks = 0; ks < 8; ++ks) {                 // A[m=l16][k=quad*8+j]
        bf16x8 a = *(const bf16x8*)&G[((h * 32 + ks * 4 + quad) * 17 + l16) * 8];
        #pragma unroll
        for (int ct = 0; ct < 4; ++ct)
            acc[ct] = __builtin_amdgcn_mfma_f32_16x16x32_bf16(
                a, Ws8[((h * 4 + ct) * 8 + ks) * 64 + lane], acc[ct], 0, 0, 0);
    }
    // part 2: feat[dst rows] @ W_dst[cols h*64..h*64+63]  (A from global f32)
    const float* arow_p = feat + (size_t)(base + l16) * 256;
    const bf16x8* Wd8 = (const bf16x8*)Wsw_dst;
    #pragma unroll
    for (int ks = 0; ks < 8; ++ks) {
        int k0 = ks * 32 + quad * 8;
        float4 f0 = *(const float4*)(arow_p + k0);
        float4 f1 = *(const float4*)(arow_p + k0 + 4);
        union { unsigned short u[8]; bf16x8 v; } cv;
        cv.u[0] = f2bf(f0.x); cv.u[1] = f2bf(f0.y);
        cv.u[2] = f2bf(f0.z); cv.u[3] = f2bf(f0.w);
        cv.u[4] = f2bf(f1.x); cv.u[5] = f2bf(f1.y);
        cv.u[6] = f2bf(f1.z); cv.u[7] = f2bf(f1.w);
        #pragma unroll
        for (int ct = 0; ct < 4; ++ct)
            acc[ct] = __builtin_amdgcn_mfma_f32_16x16x32_bf16(
                cv.v, Wd8[((h * 4 + ct) * 8 + ks) * 64 + lane], acc[ct], 0, 0, 0);
    }
    // store: C/D col = lane&15, row = quad*4 + reg; out written exactly once
    #pragma unroll
    for (int ct = 0; ct < 4; ++ct) {
        int col = h * 64 + ct * 16 + l16;
        float b = b_dst[col];
        #pragma unroll
        for (int r = 0; r < 4; ++r) {
            int node = base + quad * 4 + r;
            out[(size_t)node * 256 + col] = acc[ct][r] + b;
        }
    }
}

extern "C" void kernel_launch(void* const* d_in, const int* in_sizes, int n_in,
                              void* d_out, int out_size, void* d_ws, size_t ws_size,
                              hipStream_t stream) {
    const float* feat   = (const float*)d_in[0];
    const float* W_src  = (const float*)d_in[1];
    const float* W_dst  = (const float*)d_in[2];
    const float* b_dst  = (const float*)d_in[3];
    const float* Wa_src = (const float*)d_in[4];
    const float* Wa_dst = (const float*)d_in[5];
    const int*   src    = (const int*)d_in[6];
    const int*   dst    = (const int*)d_in[7];
    float* out = (float*)d_out;

    // ws footprint: 3,862,148 B (known-good from R3; ws_size < 55 MB)
    char* ws = (char*)d_ws;
    unsigned short* Wsw_src = (unsigned short*)(ws);               // 131,072 B
    unsigned short* Wsw_dst = (unsigned short*)(ws + 131072);      // 131,072 B
    float* a_src            = (float*)(ws + 262144);               // 1,600,000 B
    float* a_dst            = (float*)(ws + 1862144);              // 1,600,000 B
    int*   rp               = (int*)(ws + 3462144);                // 400,004 B

    hipLaunchKernelGGL(cvt_w_k,  dim3(512),   dim3(256), 0, stream, W_src, W_dst, Wsw_src, Wsw_dst);
    hipLaunchKernelGGL(aproj_k,  dim3(25000), dim3(256), 0, stream, feat, Wa_src, Wa_dst, a_src, a_dst);
    hipLaunchKernelGGL(rowptr_k, dim3(391),   dim3(256), 0, stream, dst, rp);
    hipLaunchKernelGGL(agg_k,    dim3(6250),  dim3(256), 0, stream, src, rp, a_src, a_dst,
                       feat, Wsw_src, Wsw_dst, b_dst, out);
}